// Round 4
// baseline (5609.061 us; speedup 1.0000x reference)
//
#include <hip/hip_runtime.h>
#include <hip/hip_bf16.h>

// Problem constants (hardcoded in the reference module)
#define P 4
#define NN 100000
#define MM 50000
#define EE 400000
#define DD 128
#define ROWS 32

#define SCH 4096           // scan chunk
#define NCH 13             // ceil(MM / SCH)

typedef __attribute__((ext_vector_type(8))) short bf16x8;   // 8 bf16 in 4 VGPRs
typedef __attribute__((ext_vector_type(4))) float f32x4;    // MFMA accumulator

__device__ inline unsigned short bf16u(float x) {
    __hip_bfloat16 h = __float2bfloat16(x);                 // RNE
    return __builtin_bit_cast(unsigned short, h);
}
__device__ inline float bf16f(unsigned short u) {
    return __builtin_bit_cast(float, (unsigned)u << 16);
}

// ---------------------------------------------------------------------------
// K1: per-(s,d) pair: count original-dst degree (mean weights). One atomic/edge.
__global__ __launch_bounds__(256) void k_count(const int* __restrict__ edge_dst,
                                               int* __restrict__ deg_orig) {
    int i = blockIdx.x * 256 + threadIdx.x;
    if (i >= P * P * EE) return;
    int pair = i / EE;
    atomicAdd(&deg_orig[pair * MM + edge_dst[i]], 1);
}

// K1b: derive merged-row counts from deg_orig and self-term counts.
__global__ __launch_bounds__(256) void k_derive(const int* __restrict__ merge,
                                                const int* __restrict__ deg_orig,
                                                int* __restrict__ cnt_n,
                                                int* __restrict__ cnt_s) {
    int i = blockIdx.x * 256 + threadIdx.x;
    if (i >= P * P * MM) return;
    int pair = i / MM;
    int r = i - pair * MM;
    int s = pair >> 2, d = pair & 3;
    int m = (s == d) ? r : merge[i];
    atomicAdd(&cnt_n[pair * MM + m], deg_orig[i]);
    atomicAdd(&cnt_s[pair * MM + m], 1);
}

// ---------------------------------------------------------------------------
// K2a: per-chunk partial sums (grid = 2*16*NCH = 416 blocks).
__global__ __launch_bounds__(256) void k_scan1(const int* __restrict__ cnt_n,
                                               const int* __restrict__ cnt_s,
                                               int* __restrict__ partial) {
    int blk = blockIdx.x;
    int chunk = blk % NCH, wp = blk / NCH;
    const int* cnt = ((wp >> 4) ? cnt_s : cnt_n) + (wp & 15) * MM;
    int base = chunk * SCH;
    int end = min(base + SCH, MM);
    int sum = 0;
    for (int i = base + (int)threadIdx.x; i < end; i += 256) sum += cnt[i];
    #pragma unroll
    for (int off = 32; off > 0; off >>= 1) sum += __shfl_down(sum, off);
    __shared__ int sh[4];
    if ((threadIdx.x & 63) == 0) sh[threadIdx.x >> 6] = sum;
    __syncthreads();
    if (threadIdx.x == 0) partial[blk] = sh[0] + sh[1] + sh[2] + sh[3];
}

// K2b: per-chunk exclusive scan + chunk offset; write rs; zero cnt (cursor).
__global__ __launch_bounds__(256) void k_scan2(int* __restrict__ cnt_n,
                                               int* __restrict__ rs_n,
                                               int* __restrict__ cnt_s,
                                               int* __restrict__ rs_s,
                                               const int* __restrict__ partial) {
    int blk = blockIdx.x;
    int chunk = blk % NCH, wp = blk / NCH;
    int which = wp >> 4, pair = wp & 15;
    int* cnt = (which ? cnt_s : cnt_n) + pair * MM;
    int* rs  = (which ? rs_s : rs_n) + pair * (MM + 1);
    __shared__ int sh[256];
    __shared__ int soff;
    if (threadIdx.x == 0) {
        int o = 0;
        for (int c = 0; c < chunk; ++c) o += partial[wp * NCH + c];
        soff = o;
        if (chunk == NCH - 1) rs[MM] = o + partial[wp * NCH + chunk];
    }
    int base = chunk * SCH + (int)threadIdx.x * 16;
    int v[16]; int run = 0;
    #pragma unroll
    for (int j = 0; j < 16; ++j) {
        int i = base + j;
        int c = (i < MM) ? cnt[i] : 0;
        v[j] = run;
        run += c;
    }
    sh[threadIdx.x] = run;
    __syncthreads();
    for (int off = 1; off < 256; off <<= 1) {
        int t = (threadIdx.x >= (unsigned)off) ? sh[threadIdx.x - off] : 0;
        __syncthreads();
        sh[threadIdx.x] += t;
        __syncthreads();
    }
    int texc = sh[threadIdx.x] - run;
    int o = soff + texc;
    #pragma unroll
    for (int j = 0; j < 16; ++j) {
        int i = base + j;
        if (i < MM) { rs[i] = o + v[j]; cnt[i] = 0; }
    }
}

// ---------------------------------------------------------------------------
// K3: counting-sort neigh edges into merged-dst CSR. Edge word packs
//     src (<2^17) | row-in-block (m&31) << 20; weight in .y.
__global__ __launch_bounds__(256) void k_fill(const int* __restrict__ edge_src,
                                              const int* __restrict__ edge_dst,
                                              const int* __restrict__ merge,
                                              const int* __restrict__ deg_orig,
                                              const int* __restrict__ rs_n,
                                              int* __restrict__ cur_n,
                                              int2* __restrict__ csp) {
    int i = blockIdx.x * 256 + threadIdx.x;
    if (i >= P * P * EE) return;
    int pair = i / EE;
    int s = pair >> 2, d = pair & 3;
    int od = edge_dst[i];
    int m = (s == d) ? od : merge[pair * MM + od];
    float w = 1.0f / fmaxf((float)deg_orig[pair * MM + od], 1.0f);
    int pos = rs_n[pair * (MM + 1) + m] + atomicAdd(&cur_n[pair * MM + m], 1);
    int2 e; e.x = edge_src[i] | ((m & 31) << 20); e.y = __float_as_int(w);
    csp[(size_t)pair * EE + pos] = e;
}

// K3b: self-term CSR; value packs r (<2^16) | row-in-block << 20.
__global__ __launch_bounds__(256) void k_fill_self(const int* __restrict__ merge,
                                                   const int* __restrict__ rs_s,
                                                   int* __restrict__ cur_s,
                                                   int* __restrict__ css) {
    int i = blockIdx.x * 256 + threadIdx.x;
    if (i >= P * P * MM) return;
    int pair = i / MM;
    int r = i - pair * MM;
    int s = pair >> 2, d = pair & 3;
    int m = (s == d) ? r : merge[i];
    int pos = rs_s[pair * (MM + 1) + m] + atomicAdd(&cur_s[pair * MM + m], 1);
    css[pair * MM + pos] = r | ((m & 31) << 20);
}

// ---------------------------------------------------------------------------
// K3c: split weights into hi/lo bf16, packed fragment-ready:
//      Bpk[s][hl(2)][kchunk(32)][col(128)][8k]  (chunks 0-15 = W_self rows,
//      16-31 = W_neigh rows). 512 KB; overlaid on dead deg_orig space.
__global__ __launch_bounds__(256) void k_pack_w(const float* __restrict__ Ws,
                                                const float* __restrict__ Wn,
                                                unsigned short* __restrict__ Bpk) {
    int t = blockIdx.x * 256 + threadIdx.x;     // 4s * 32c * 128col = 16384
    if (t >= 4 * 32 * 128) return;
    int s = t >> 12;
    int rem = t & 4095;                         // c*128 + col
    int c = rem >> 7, col = rem & 127;
    const float* W = (c < 16) ? (Ws + (size_t)s * DD * DD + (c * 8) * DD + col)
                              : (Wn + (size_t)s * DD * DD + ((c - 16) * 8) * DD + col);
    size_t ohi = ((size_t)(s * 2 + 0) * 4096 + rem) * 8;
    size_t olo = ((size_t)(s * 2 + 1) * 4096 + rem) * 8;
    #pragma unroll
    for (int j = 0; j < 8; ++j) {
        float v = W[(size_t)j * DD];
        unsigned short h = bf16u(v);
        unsigned short l = bf16u(v - bf16f(h));
        Bpk[ohi + j] = h;
        Bpk[olo + j] = l;
    }
}

// ---------------------------------------------------------------------------
// K4: fused per-d kernel. EDGE-PARALLEL gather: block's 32 rows own a
//     contiguous CSR slice; each wave takes 8-edge chunks (scalar idx loads,
//     8 feature loads in flight, no dependent chains, no per-thread
//     accumulator state) and ds_add_f32's into an fp32 LDS A-tile.
//     s==d self term = tile initializer (identity). MFMA phase reads fp32
//     from LDS, hi/lo bf16 split in-register, 16x16x32 bf16 MFMA (3 products).
__global__ __launch_bounds__(256, 5) void k_fused(const float* __restrict__ x_all,
                                                  const float* __restrict__ b_all,
                                                  const int* __restrict__ rs_n_all,
                                                  const int2* __restrict__ csp_all,
                                                  const int* __restrict__ rs_s_all,
                                                  const int* __restrict__ css_all,
                                                  const unsigned short* __restrict__ Bpk,
                                                  float* __restrict__ out) {
    int d = blockIdx.y;
    int m0 = blockIdx.x * ROWS;
    int tid = threadIdx.x;
    int lane = tid & 63, wv = tid >> 6;
    int l15 = lane & 15, kg = lane >> 4;
    int mtop = min(m0 + ROWS, MM);

    // fp32 A tile [32 rows][256 k], row stride 1024 B.
    // XOR-swizzle byte ^= ((row&7)<<4) on 16B granules (write & read sides).
    __shared__ char lds[32768];

    f32x4 acc[2][2];
    f32x4 zero = {0.f, 0.f, 0.f, 0.f};
    acc[0][0] = zero; acc[0][1] = zero; acc[1][0] = zero; acc[1][1] = zero;

    int voff = lane * 8;                        // float2 byte offset per lane

    for (int s = 0; s < P; ++s) {
        int pair = s * P + d;
        const float* x   = x_all + (size_t)s * NN * DD;
        const int* rsn   = rs_n_all + (size_t)pair * (MM + 1);
        const int2* csp  = csp_all + (size_t)pair * EE;
        const int* rss   = rs_s_all + (size_t)pair * (MM + 1);
        const int* css   = css_all + (size_t)pair * MM;

        // ---- init tile: self half = x row (s==d identity) or 0; neigh half = 0
        for (int j = tid; j < 2048; j += 256) {       // 2048 16B granules
            int row = j >> 6, c4 = j & 63;            // c4: 16B chunk in row
            float4 v = make_float4(0.f, 0.f, 0.f, 0.f);
            if (s == d && c4 < 32) {
                int m = m0 + row;
                if (m < MM) v = *(const float4*)(x + (size_t)m * DD + c4 * 4);
            }
            *(float4*)(lds + row * 1024 + ((c4 * 16) ^ ((row & 7) << 4))) = v;
        }
        __syncthreads();

        // ---- neigh edges: contiguous slice [nb, ne), wave-strided 8-chunks
        int nb = __builtin_amdgcn_readfirstlane(rsn[m0]);
        int ne = __builtin_amdgcn_readfirstlane(rsn[mtop]);
        for (int eb = nb + wv * 8; eb < ne; eb += 32) {
            int e0 = __builtin_amdgcn_readfirstlane(eb);
            int lim = ne - 1;
            int2 ed[8];
            #pragma unroll
            for (int q = 0; q < 8; ++q) ed[q] = csp[min(e0 + q, lim)];
            float2 f[8];
            #pragma unroll
            for (int q = 0; q < 8; ++q) {
                int src = ed[q].x & 0xFFFFF;
                f[q] = *(const float2*)((const char*)(x + (size_t)src * DD) + voff);
            }
            #pragma unroll
            for (int q = 0; q < 8; ++q) {
                if (e0 + q < ne) {
                    int row = ((unsigned)ed[q].x) >> 20;
                    float w = __int_as_float(ed[q].y);
                    char* p = lds + row * 1024 + (((512 + voff)) ^ ((row & 7) << 4));
                    atomicAdd((float*)p, w * f[q].x);
                    atomicAdd((float*)(p + 4), w * f[q].y);
                }
            }
        }

        // ---- self edges (s != d): same machinery, w = 1, cols 0:128
        if (s != d) {
            int sb = __builtin_amdgcn_readfirstlane(rss[m0]);
            int se = __builtin_amdgcn_readfirstlane(rss[mtop]);
            for (int eb = sb + wv * 8; eb < se; eb += 32) {
                int e0 = __builtin_amdgcn_readfirstlane(eb);
                int lim = se - 1;
                int sed[8];
                #pragma unroll
                for (int q = 0; q < 8; ++q) sed[q] = css[min(e0 + q, lim)];
                float2 f[8];
                #pragma unroll
                for (int q = 0; q < 8; ++q) {
                    int src = sed[q] & 0xFFFFF;
                    f[q] = *(const float2*)((const char*)(x + (size_t)src * DD) + voff);
                }
                #pragma unroll
                for (int q = 0; q < 8; ++q) {
                    if (e0 + q < se) {
                        int row = ((unsigned)sed[q]) >> 20;
                        char* p = lds + row * 1024 + ((voff) ^ ((row & 7) << 4));
                        atomicAdd((float*)p, f[q].x);
                        atomicAdd((float*)(p + 4), f[q].y);
                    }
                }
            }
        }
        __syncthreads();

        // ---- MFMA GEMM: acc[32][128] += A[32][256] @ [Ws[s]; Wn[s]]
        // read fp32 A from LDS, split hi/lo bf16 in-register.
        {
            int row0 = l15, row1 = 16 + l15;
            int xr = (l15 & 7) << 4;
            const bf16x8* Bh = (const bf16x8*)(Bpk + (size_t)(s * 2 + 0) * 4096 * 8);
            const bf16x8* Bl = (const bf16x8*)(Bpk + (size_t)(s * 2 + 1) * 4096 * 8);
            int colbase = wv * 32 + l15;
            #pragma unroll
            for (int kk = 0; kk < 8; ++kk) {
                int c = kk * 4 + kg;                 // bf16 16B-chunk id (8 k's)
                int b0 = (c * 32) ^ xr;
                int b1 = (c * 32 + 16) ^ xr;
                float4 p00 = *(const float4*)(lds + row0 * 1024 + b0);
                float4 p01 = *(const float4*)(lds + row0 * 1024 + b1);
                float4 p10 = *(const float4*)(lds + row1 * 1024 + b0);
                float4 p11 = *(const float4*)(lds + row1 * 1024 + b1);
                bf16x8 ah0, al0, ah1, al1;
                float pv0[8] = {p00.x, p00.y, p00.z, p00.w, p01.x, p01.y, p01.z, p01.w};
                float pv1[8] = {p10.x, p10.y, p10.z, p10.w, p11.x, p11.y, p11.z, p11.w};
                #pragma unroll
                for (int j = 0; j < 8; ++j) {
                    unsigned short h0 = bf16u(pv0[j]);
                    ah0[j] = (short)h0;
                    al0[j] = (short)bf16u(pv0[j] - bf16f(h0));
                    unsigned short h1 = bf16u(pv1[j]);
                    ah1[j] = (short)h1;
                    al1[j] = (short)bf16u(pv1[j] - bf16f(h1));
                }
                size_t bo = (size_t)c * 128 + colbase;
                bf16x8 bh0 = Bh[bo];
                bf16x8 bh1 = Bh[bo + 16];
                bf16x8 bl0 = Bl[bo];
                bf16x8 bl1 = Bl[bo + 16];
                acc[0][0] = __builtin_amdgcn_mfma_f32_16x16x32_bf16(ah0, bh0, acc[0][0], 0, 0, 0);
                acc[0][1] = __builtin_amdgcn_mfma_f32_16x16x32_bf16(ah0, bh1, acc[0][1], 0, 0, 0);
                acc[1][0] = __builtin_amdgcn_mfma_f32_16x16x32_bf16(ah1, bh0, acc[1][0], 0, 0, 0);
                acc[1][1] = __builtin_amdgcn_mfma_f32_16x16x32_bf16(ah1, bh1, acc[1][1], 0, 0, 0);
                acc[0][0] = __builtin_amdgcn_mfma_f32_16x16x32_bf16(al0, bh0, acc[0][0], 0, 0, 0);
                acc[0][1] = __builtin_amdgcn_mfma_f32_16x16x32_bf16(al0, bh1, acc[0][1], 0, 0, 0);
                acc[1][0] = __builtin_amdgcn_mfma_f32_16x16x32_bf16(al1, bh0, acc[1][0], 0, 0, 0);
                acc[1][1] = __builtin_amdgcn_mfma_f32_16x16x32_bf16(al1, bh1, acc[1][1], 0, 0, 0);
                acc[0][0] = __builtin_amdgcn_mfma_f32_16x16x32_bf16(ah0, bl0, acc[0][0], 0, 0, 0);
                acc[0][1] = __builtin_amdgcn_mfma_f32_16x16x32_bf16(ah0, bl1, acc[0][1], 0, 0, 0);
                acc[1][0] = __builtin_amdgcn_mfma_f32_16x16x32_bf16(ah1, bl0, acc[1][0], 0, 0, 0);
                acc[1][1] = __builtin_amdgcn_mfma_f32_16x16x32_bf16(ah1, bl1, acc[1][1], 0, 0, 0);
            }
        }

        // ---- bias: each contributing source row brings one b[s]
        {
            float bv0 = b_all[(size_t)s * DD + wv * 32 + l15];
            float bv1 = b_all[(size_t)s * DD + wv * 32 + 16 + l15];
            #pragma unroll
            for (int rt = 0; rt < 2; ++rt) {
                int mb = m0 + rt * 16 + kg * 4;
                #pragma unroll
                for (int r = 0; r < 4; ++r) {
                    int m = mb + r;
                    if (m < MM) {
                        float cf = (float)(rss[m + 1] - rss[m]);
                        acc[rt][0][r] += cf * bv0;
                        acc[rt][1][r] += cf * bv1;
                    }
                }
            }
        }
        __syncthreads();   // before next s overwrites LDS
    }

    // ---- store. D layout: col = lane&15 (+tile), row = (lane>>4)*4 + reg (+tile)
    float* outd = out + (size_t)d * MM * DD;
    #pragma unroll
    for (int rt = 0; rt < 2; ++rt) {
        #pragma unroll
        for (int r = 0; r < 4; ++r) {
            int m = m0 + rt * 16 + kg * 4 + r;
            if (m >= MM) continue;
            float* o = outd + (size_t)m * DD + wv * 32 + l15;
            o[0]  = acc[rt][0][r];
            o[16] = acc[rt][1][r];
        }
    }
}

// ---------------------------------------------------------------------------
extern "C" void kernel_launch(void* const* d_in, const int* in_sizes, int n_in,
                              void* d_out, int out_size, void* d_ws, size_t ws_size,
                              hipStream_t stream) {
    const float* x     = (const float*)d_in[0];   // [P][N][D]
    const float* Ws    = (const float*)d_in[1];   // [P][D][D]
    const float* Wn    = (const float*)d_in[2];   // [P][D][D]
    const float* b     = (const float*)d_in[3];   // [P][D]
    const int*   esrc  = (const int*)d_in[4];     // [P][P][E]
    const int*   edst  = (const int*)d_in[5];     // [P][P][E]
    const int*   merge = (const int*)d_in[6];     // [P][P][M]
    float* out = (float*)d_out;                   // [P][M][D]

    // workspace layout (~70.4 MB total, unchanged footprint):
    int* deg_orig = (int*)d_ws;                   // [16*M]; dead after k_fill -> Bpk
    int* cnt_n    = deg_orig + 16 * MM;           // [16*M] counts -> cursor
    int* cnt_s    = cnt_n + 16 * MM;              // [16*M] counts -> cursor
    int* rs_n     = cnt_s + 16 * MM;              // [16*(M+1)]
    int* rs_s     = rs_n + 16 * (MM + 1);         // [16*(M+1)]
    int2* csp     = (int2*)(rs_s + 16 * (MM + 1));// [16*E] packed (src|row<<20, w)
    int* css      = (int*)(csp + (size_t)16 * EE);// [16*M] packed (r|row<<20)
    int* partial  = (int*)csp;                    // scan partials overlay (pre-fill)
    unsigned short* Bpk = (unsigned short*)d_ws;  // overlay on deg_orig

    hipMemsetAsync(d_ws, 0, sizeof(int) * (size_t)16 * MM * 3, stream);  // deg+cnt_n+cnt_s

    int eblocks = (P * P * EE + 255) / 256;       // 25000
    int mblocks16 = (P * P * MM + 255) / 256;     // 3125
    k_count<<<eblocks, 256, 0, stream>>>(edst, deg_orig);
    k_derive<<<mblocks16, 256, 0, stream>>>(merge, deg_orig, cnt_n, cnt_s);
    k_scan1<<<2 * 16 * NCH, 256, 0, stream>>>(cnt_n, cnt_s, partial);
    k_scan2<<<2 * 16 * NCH, 256, 0, stream>>>(cnt_n, rs_n, cnt_s, rs_s, partial);
    k_fill<<<eblocks, 256, 0, stream>>>(esrc, edst, merge, deg_orig, rs_n, cnt_n, csp);
    k_fill_self<<<mblocks16, 256, 0, stream>>>(merge, rs_s, cnt_s, css);
    k_pack_w<<<64, 256, 0, stream>>>(Ws, Wn, Bpk);  // overwrites deg_orig (dead)

    dim3 gfused((MM + ROWS - 1) / ROWS, P);       // (1563, 4)
    k_fused<<<gfused, 256, 0, stream>>>(x, b, rs_n, csp, rs_s, css, Bpk, out);
}

// Round 5
// 1774.466 us; speedup vs baseline: 3.1610x; 3.1610x over previous
//
#include <hip/hip_runtime.h>
#include <hip/hip_bf16.h>

// Problem constants (hardcoded in the reference module)
#define P 4
#define NN 100000
#define MM 50000
#define EE 400000
#define DD 128
#define ROWS 32

#define SCH 4096           // scan chunk
#define NCH 13             // ceil(MM / SCH)

typedef __attribute__((ext_vector_type(8))) short bf16x8;   // 8 bf16 in 4 VGPRs
typedef __attribute__((ext_vector_type(4))) float f32x4;    // MFMA accumulator

__device__ inline unsigned short bf16u(float x) {
    __hip_bfloat16 h = __float2bfloat16(x);                 // RNE
    return __builtin_bit_cast(unsigned short, h);
}
__device__ inline float bf16f(unsigned short u) {
    return __builtin_bit_cast(float, (unsigned)u << 16);
}

// ---------------------------------------------------------------------------
// K1: per-(s,d) pair: count original-dst degree (mean weights). One atomic/edge.
__global__ __launch_bounds__(256) void k_count(const int* __restrict__ edge_dst,
                                               int* __restrict__ deg_orig) {
    int i = blockIdx.x * 256 + threadIdx.x;
    if (i >= P * P * EE) return;
    int pair = i / EE;
    atomicAdd(&deg_orig[pair * MM + edge_dst[i]], 1);
}

// K1b: derive merged-row counts from deg_orig and self-term counts.
__global__ __launch_bounds__(256) void k_derive(const int* __restrict__ merge,
                                                const int* __restrict__ deg_orig,
                                                int* __restrict__ cnt_n,
                                                int* __restrict__ cnt_s) {
    int i = blockIdx.x * 256 + threadIdx.x;
    if (i >= P * P * MM) return;
    int pair = i / MM;
    int r = i - pair * MM;
    int s = pair >> 2, d = pair & 3;
    int m = (s == d) ? r : merge[i];
    atomicAdd(&cnt_n[pair * MM + m], deg_orig[i]);
    atomicAdd(&cnt_s[pair * MM + m], 1);
}

// ---------------------------------------------------------------------------
// K2a: per-chunk partial sums (grid = 2*16*NCH = 416 blocks).
__global__ __launch_bounds__(256) void k_scan1(const int* __restrict__ cnt_n,
                                               const int* __restrict__ cnt_s,
                                               int* __restrict__ partial) {
    int blk = blockIdx.x;
    int chunk = blk % NCH, wp = blk / NCH;
    const int* cnt = ((wp >> 4) ? cnt_s : cnt_n) + (wp & 15) * MM;
    int base = chunk * SCH;
    int end = min(base + SCH, MM);
    int sum = 0;
    for (int i = base + (int)threadIdx.x; i < end; i += 256) sum += cnt[i];
    #pragma unroll
    for (int off = 32; off > 0; off >>= 1) sum += __shfl_down(sum, off);
    __shared__ int sh[4];
    if ((threadIdx.x & 63) == 0) sh[threadIdx.x >> 6] = sum;
    __syncthreads();
    if (threadIdx.x == 0) partial[blk] = sh[0] + sh[1] + sh[2] + sh[3];
}

// K2b: per-chunk exclusive scan + chunk offset; write rs; zero cnt (cursor).
__global__ __launch_bounds__(256) void k_scan2(int* __restrict__ cnt_n,
                                               int* __restrict__ rs_n,
                                               int* __restrict__ cnt_s,
                                               int* __restrict__ rs_s,
                                               const int* __restrict__ partial) {
    int blk = blockIdx.x;
    int chunk = blk % NCH, wp = blk / NCH;
    int which = wp >> 4, pair = wp & 15;
    int* cnt = (which ? cnt_s : cnt_n) + pair * MM;
    int* rs  = (which ? rs_s : rs_n) + pair * (MM + 1);
    __shared__ int sh[256];
    __shared__ int soff;
    if (threadIdx.x == 0) {
        int o = 0;
        for (int c = 0; c < chunk; ++c) o += partial[wp * NCH + c];
        soff = o;
        if (chunk == NCH - 1) rs[MM] = o + partial[wp * NCH + chunk];
    }
    int base = chunk * SCH + (int)threadIdx.x * 16;
    int v[16]; int run = 0;
    #pragma unroll
    for (int j = 0; j < 16; ++j) {
        int i = base + j;
        int c = (i < MM) ? cnt[i] : 0;
        v[j] = run;
        run += c;
    }
    sh[threadIdx.x] = run;
    __syncthreads();
    for (int off = 1; off < 256; off <<= 1) {
        int t = (threadIdx.x >= (unsigned)off) ? sh[threadIdx.x - off] : 0;
        __syncthreads();
        sh[threadIdx.x] += t;
        __syncthreads();
    }
    int texc = sh[threadIdx.x] - run;
    int o = soff + texc;
    #pragma unroll
    for (int j = 0; j < 16; ++j) {
        int i = base + j;
        if (i < MM) { rs[i] = o + v[j]; cnt[i] = 0; }
    }
}

// ---------------------------------------------------------------------------
// K3: counting-sort neigh edges into merged-dst CSR; (src, weight) packed int2.
__global__ __launch_bounds__(256) void k_fill(const int* __restrict__ edge_src,
                                              const int* __restrict__ edge_dst,
                                              const int* __restrict__ merge,
                                              const int* __restrict__ deg_orig,
                                              const int* __restrict__ rs_n,
                                              int* __restrict__ cur_n,
                                              int2* __restrict__ csp) {
    int i = blockIdx.x * 256 + threadIdx.x;
    if (i >= P * P * EE) return;
    int pair = i / EE;
    int s = pair >> 2, d = pair & 3;
    int od = edge_dst[i];
    int m = (s == d) ? od : merge[pair * MM + od];
    float w = 1.0f / fmaxf((float)deg_orig[pair * MM + od], 1.0f);
    int pos = rs_n[pair * (MM + 1) + m] + atomicAdd(&cur_n[pair * MM + m], 1);
    int2 e; e.x = edge_src[i]; e.y = __float_as_int(w);
    csp[(size_t)pair * EE + pos] = e;
}

// K3b: self-term CSR (row r of x[s][:M] contributes to merged row m).
__global__ __launch_bounds__(256) void k_fill_self(const int* __restrict__ merge,
                                                   const int* __restrict__ rs_s,
                                                   int* __restrict__ cur_s,
                                                   int* __restrict__ css) {
    int i = blockIdx.x * 256 + threadIdx.x;
    if (i >= P * P * MM) return;
    int pair = i / MM;
    int r = i - pair * MM;
    int s = pair >> 2, d = pair & 3;
    int m = (s == d) ? r : merge[i];
    int pos = rs_s[pair * (MM + 1) + m] + atomicAdd(&cur_s[pair * MM + m], 1);
    css[pair * MM + pos] = r;
}

// ---------------------------------------------------------------------------
// K3c: split weights into hi/lo bf16, packed fragment-ready:
//      Bpk[s][hl(2)][kchunk(32)][col(128)][8k]  (chunks 0-15 = W_self rows,
//      16-31 = W_neigh rows). 512 KB; overlaid on dead deg_orig space.
__global__ __launch_bounds__(256) void k_pack_w(const float* __restrict__ Ws,
                                                const float* __restrict__ Wn,
                                                unsigned short* __restrict__ Bpk) {
    int t = blockIdx.x * 256 + threadIdx.x;     // 4s * 32c * 128col = 16384
    if (t >= 4 * 32 * 128) return;
    int s = t >> 12;
    int rem = t & 4095;                         // c*128 + col
    int c = rem >> 7, col = rem & 127;
    const float* W = (c < 16) ? (Ws + (size_t)s * DD * DD + (c * 8) * DD + col)
                              : (Wn + (size_t)s * DD * DD + ((c - 16) * 8) * DD + col);
    size_t ohi = ((size_t)(s * 2 + 0) * 4096 + rem) * 8;
    size_t olo = ((size_t)(s * 2 + 1) * 4096 + rem) * 8;
    #pragma unroll
    for (int j = 0; j < 8; ++j) {
        float v = W[(size_t)j * DD];
        unsigned short h = bf16u(v);
        unsigned short l = bf16u(v - bf16f(h));
        Bpk[ohi + j] = h;
        Bpk[olo + j] = l;
    }
}

// ---------------------------------------------------------------------------
// K4: fused per-d kernel, 512 threads / 8 waves. Round-1's proven row-serial
//     gather, but each wave owns only 4 rows (halved latency chain) and
//     32 waves/CU resident (4 blocks x 32KB LDS). s==d self term is a direct
//     x[m] load. GEMM: each wave does one 16-col panel via 16x16x32 bf16
//     MFMA (hi*hi + lo*hi + hi*lo, fp32 accum).
__global__ __launch_bounds__(512, 8) void k_fused(const float* __restrict__ x_all,
                                                  const float* __restrict__ b_all,
                                                  const int* __restrict__ rs_n_all,
                                                  const int2* __restrict__ csp_all,
                                                  const int* __restrict__ rs_s_all,
                                                  const int* __restrict__ css_all,
                                                  const unsigned short* __restrict__ Bpk,
                                                  float* __restrict__ out) {
    int d = blockIdx.y;
    int m0 = blockIdx.x * ROWS;
    int tid = threadIdx.x;
    int lane = tid & 63, wv = tid >> 6;         // wv in 0..7
    int l15 = lane & 15, kg = lane >> 4;

    // A_hi [32 rows][256 k] bf16 @0, A_lo @16384. Row stride 512 B.
    // XOR-swizzle byte ^= ((row&7)<<4) to break the 512B-stride bank conflict.
    __shared__ char lds[32768];

    f32x4 acc[2];
    f32x4 zero = {0.f, 0.f, 0.f, 0.f};
    acc[0] = zero; acc[1] = zero;

    for (int s = 0; s < P; ++s) {
        int pair = s * P + d;
        const float* x   = x_all + (size_t)s * NN * DD;
        const int* rsn   = rs_n_all + (size_t)pair * (MM + 1);
        const int2* csp  = csp_all + (size_t)pair * EE;
        const int* rss   = rs_s_all + (size_t)pair * (MM + 1);
        const int* css   = css_all + (size_t)pair * MM;

        // ---- gather: wave wv handles rows wv, wv+8, wv+16, wv+24.
        //      lane covers cols {2l, 2l+1}.
        for (int r = wv; r < ROWS; r += 8) {
            int m = m0 + r;
            float sx = 0.f, sy = 0.f, nx = 0.f, ny = 0.f;
            if (m < MM) {
                // self-scatter sum: identity on the diagonal, CSR else
                if (s == d) {
                    float2 v = ((const float2*)(x + (size_t)m * DD))[lane];
                    sx = v.x; sy = v.y;
                } else {
                    int e0 = rss[m], e1 = rss[m + 1];
                    for (int e = e0; e < e1; ++e) {
                        float2 v = ((const float2*)(x + (size_t)css[e] * DD))[lane];
                        sx += v.x; sy += v.y;
                    }
                }
                // weighted neigh sum (avg 8 rows), 4-wide unroll for MLP
                int e0 = rsn[m], e1 = rsn[m + 1];
                int e = e0;
                for (; e + 4 <= e1; e += 4) {
                    int2 c0 = csp[e], c1 = csp[e + 1], c2 = csp[e + 2], c3 = csp[e + 3];
                    float2 v0 = ((const float2*)(x + (size_t)c0.x * DD))[lane];
                    float2 v1 = ((const float2*)(x + (size_t)c1.x * DD))[lane];
                    float2 v2 = ((const float2*)(x + (size_t)c2.x * DD))[lane];
                    float2 v3 = ((const float2*)(x + (size_t)c3.x * DD))[lane];
                    float w0 = __int_as_float(c0.y), w1 = __int_as_float(c1.y);
                    float w2 = __int_as_float(c2.y), w3 = __int_as_float(c3.y);
                    nx += w0 * v0.x + w1 * v1.x + w2 * v2.x + w3 * v3.x;
                    ny += w0 * v0.y + w1 * v1.y + w2 * v2.y + w3 * v3.y;
                }
                for (; e < e1; ++e) {
                    int2 c = csp[e];
                    float w = __int_as_float(c.y);
                    float2 v = ((const float2*)(x + (size_t)c.x * DD))[lane];
                    nx += w * v.x; ny += w * v.y;
                }
            }
            // hi/lo bf16 split -> swizzled LDS. self half k[0,128), neigh k[128,256)
            int xr = (r & 7) << 4;
            int rbase = r * 512;
            unsigned short hx = bf16u(sx), hy = bf16u(sy);
            unsigned short lx = bf16u(sx - bf16f(hx)), ly = bf16u(sy - bf16f(hy));
            *(unsigned*)(lds + rbase + ((4 * lane) ^ xr))         = hx | ((unsigned)hy << 16);
            *(unsigned*)(lds + 16384 + rbase + ((4 * lane) ^ xr)) = lx | ((unsigned)ly << 16);
            hx = bf16u(nx); hy = bf16u(ny);
            lx = bf16u(nx - bf16f(hx)); ly = bf16u(ny - bf16f(hy));
            *(unsigned*)(lds + rbase + ((256 + 4 * lane) ^ xr))         = hx | ((unsigned)hy << 16);
            *(unsigned*)(lds + 16384 + rbase + ((256 + 4 * lane) ^ xr)) = lx | ((unsigned)ly << 16);
        }
        __syncthreads();

        // ---- MFMA GEMM: acc[32][128] += A[32][256] @ [Ws[s]; Wn[s]]
        // wave wv -> cols [wv*16, wv*16+16); row tiles {0-15, 16-31}.
        {
            int row0 = l15, row1 = 16 + l15;
            int xr = (l15 & 7) << 4;
            const bf16x8* Bh = (const bf16x8*)(Bpk + (size_t)(s * 2 + 0) * 4096 * 8);
            const bf16x8* Bl = (const bf16x8*)(Bpk + (size_t)(s * 2 + 1) * 4096 * 8);
            int colbase = wv * 16 + l15;
            #pragma unroll
            for (int kk = 0; kk < 8; ++kk) {
                int c = kk * 4 + kg;
                int co = (c * 16) ^ xr;
                bf16x8 ah0 = *(const bf16x8*)(lds + row0 * 512 + co);
                bf16x8 ah1 = *(const bf16x8*)(lds + row1 * 512 + co);
                bf16x8 al0 = *(const bf16x8*)(lds + 16384 + row0 * 512 + co);
                bf16x8 al1 = *(const bf16x8*)(lds + 16384 + row1 * 512 + co);
                size_t bo = (size_t)c * 128 + colbase;
                bf16x8 bh = Bh[bo];
                bf16x8 bl = Bl[bo];
                acc[0] = __builtin_amdgcn_mfma_f32_16x16x32_bf16(ah0, bh, acc[0], 0, 0, 0);
                acc[1] = __builtin_amdgcn_mfma_f32_16x16x32_bf16(ah1, bh, acc[1], 0, 0, 0);
                acc[0] = __builtin_amdgcn_mfma_f32_16x16x32_bf16(al0, bh, acc[0], 0, 0, 0);
                acc[1] = __builtin_amdgcn_mfma_f32_16x16x32_bf16(al1, bh, acc[1], 0, 0, 0);
                acc[0] = __builtin_amdgcn_mfma_f32_16x16x32_bf16(ah0, bl, acc[0], 0, 0, 0);
                acc[1] = __builtin_amdgcn_mfma_f32_16x16x32_bf16(ah1, bl, acc[1], 0, 0, 0);
            }
        }

        // ---- bias: each contributing source row brings one b[s]
        {
            float bv = b_all[(size_t)s * DD + wv * 16 + l15];
            #pragma unroll
            for (int rt = 0; rt < 2; ++rt) {
                int mb = m0 + rt * 16 + kg * 4;
                #pragma unroll
                for (int r = 0; r < 4; ++r) {
                    int m = mb + r;
                    if (m < MM) {
                        float cf = (float)(rss[m + 1] - rss[m]);
                        acc[rt][r] += cf * bv;
                    }
                }
            }
        }
        __syncthreads();   // before next s overwrites LDS
    }

    // ---- store. D layout: col = lane&15 (+tile), row = (lane>>4)*4 + reg (+tile)
    float* outd = out + (size_t)d * MM * DD;
    #pragma unroll
    for (int rt = 0; rt < 2; ++rt) {
        #pragma unroll
        for (int r = 0; r < 4; ++r) {
            int m = m0 + rt * 16 + kg * 4 + r;
            if (m >= MM) continue;
            outd[(size_t)m * DD + wv * 16 + l15] = acc[rt][r];
        }
    }
}

// ---------------------------------------------------------------------------
extern "C" void kernel_launch(void* const* d_in, const int* in_sizes, int n_in,
                              void* d_out, int out_size, void* d_ws, size_t ws_size,
                              hipStream_t stream) {
    const float* x     = (const float*)d_in[0];   // [P][N][D]
    const float* Ws    = (const float*)d_in[1];   // [P][D][D]
    const float* Wn    = (const float*)d_in[2];   // [P][D][D]
    const float* b     = (const float*)d_in[3];   // [P][D]
    const int*   esrc  = (const int*)d_in[4];     // [P][P][E]
    const int*   edst  = (const int*)d_in[5];     // [P][P][E]
    const int*   merge = (const int*)d_in[6];     // [P][P][M]
    float* out = (float*)d_out;                   // [P][M][D]

    // workspace layout (~70.4 MB total, unchanged footprint):
    int* deg_orig = (int*)d_ws;                   // [16*M]; dead after k_fill -> Bpk
    int* cnt_n    = deg_orig + 16 * MM;           // [16*M] counts -> cursor
    int* cnt_s    = cnt_n + 16 * MM;              // [16*M] counts -> cursor
    int* rs_n     = cnt_s + 16 * MM;              // [16*(M+1)]
    int* rs_s     = rs_n + 16 * (MM + 1);         // [16*(M+1)]
    int2* csp     = (int2*)(rs_s + 16 * (MM + 1));// [16*E] packed (src, w)
    int* css      = (int*)(csp + (size_t)16 * EE);// [16*M]
    int* partial  = (int*)csp;                    // scan partials overlay (pre-fill)
    unsigned short* Bpk = (unsigned short*)d_ws;  // overlay on deg_orig

    hipMemsetAsync(d_ws, 0, sizeof(int) * (size_t)16 * MM * 3, stream);  // deg+cnt_n+cnt_s

    int eblocks = (P * P * EE + 255) / 256;       // 25000
    int mblocks16 = (P * P * MM + 255) / 256;     // 3125
    k_count<<<eblocks, 256, 0, stream>>>(edst, deg_orig);
    k_derive<<<mblocks16, 256, 0, stream>>>(merge, deg_orig, cnt_n, cnt_s);
    k_scan1<<<2 * 16 * NCH, 256, 0, stream>>>(cnt_n, cnt_s, partial);
    k_scan2<<<2 * 16 * NCH, 256, 0, stream>>>(cnt_n, rs_n, cnt_s, rs_s, partial);
    k_fill<<<eblocks, 256, 0, stream>>>(esrc, edst, merge, deg_orig, rs_n, cnt_n, csp);
    k_fill_self<<<mblocks16, 256, 0, stream>>>(merge, rs_s, cnt_s, css);
    k_pack_w<<<64, 256, 0, stream>>>(Ws, Wn, Bpk);  // overwrites deg_orig (dead)

    dim3 gfused((MM + ROWS - 1) / ROWS, P);       // (1563, 4)
    k_fused<<<gfused, 512, 0, stream>>>(x, b, rs_n, csp, rs_s, css, Bpk, out);
}

// Round 6
// 1720.544 us; speedup vs baseline: 3.2601x; 1.0313x over previous
//
#include <hip/hip_runtime.h>
#include <hip/hip_bf16.h>

// Problem constants (hardcoded in the reference module)
#define P 4
#define NN 100000
#define MM 50000
#define EE 400000
#define DD 128
#define ROWS 32

#define SCH 4096           // scan chunk
#define NCH 13             // ceil(MM / SCH)

typedef __attribute__((ext_vector_type(8))) short bf16x8;   // 8 bf16 in 4 VGPRs
typedef __attribute__((ext_vector_type(4))) float f32x4;    // MFMA accumulator

__device__ inline unsigned short bf16u(float x) {
    __hip_bfloat16 h = __float2bfloat16(x);                 // RNE
    return __builtin_bit_cast(unsigned short, h);
}
__device__ inline float bf16f(unsigned short u) {
    return __builtin_bit_cast(float, (unsigned)u << 16);
}

// ---------------------------------------------------------------------------
// K1: per-(s,d) pair: count original-dst degree. The atomic's RETURN value is
//     this edge's rank within its od group -> rank8[i] (deg << 255 for random data).
__global__ __launch_bounds__(256) void k_count(const int* __restrict__ edge_dst,
                                               int* __restrict__ deg_orig,
                                               unsigned char* __restrict__ rank8) {
    int i = blockIdx.x * 256 + threadIdx.x;
    if (i >= P * P * EE) return;
    int pair = i / EE;
    int r = atomicAdd(&deg_orig[pair * MM + edge_dst[i]], 1);
    rank8[i] = (unsigned char)r;
}

// K1b: derive merged-row counts. Atomic returns give deterministic offsets:
//      grpoff[pair][od] = offset of od's edge-group within merged row m;
//      selfrank[pair][r] = rank of r within m's self list.
__global__ __launch_bounds__(256) void k_derive(const int* __restrict__ merge,
                                                const int* __restrict__ deg_orig,
                                                int* __restrict__ cnt_n,
                                                int* __restrict__ cnt_s,
                                                int* __restrict__ grpoff,
                                                int* __restrict__ selfrank) {
    int i = blockIdx.x * 256 + threadIdx.x;
    if (i >= P * P * MM) return;
    int pair = i / MM;
    int r = i - pair * MM;
    int s = pair >> 2, d = pair & 3;
    int m = (s == d) ? r : merge[i];
    grpoff[i]   = atomicAdd(&cnt_n[pair * MM + m], deg_orig[i]);
    selfrank[i] = atomicAdd(&cnt_s[pair * MM + m], 1);
}

// ---------------------------------------------------------------------------
// K2a: per-chunk partial sums (grid = 2*16*NCH = 416 blocks).
__global__ __launch_bounds__(256) void k_scan1(const int* __restrict__ cnt_n,
                                               const int* __restrict__ cnt_s,
                                               int* __restrict__ partial) {
    int blk = blockIdx.x;
    int chunk = blk % NCH, wp = blk / NCH;
    const int* cnt = ((wp >> 4) ? cnt_s : cnt_n) + (wp & 15) * MM;
    int base = chunk * SCH;
    int end = min(base + SCH, MM);
    int sum = 0;
    for (int i = base + (int)threadIdx.x; i < end; i += 256) sum += cnt[i];
    #pragma unroll
    for (int off = 32; off > 0; off >>= 1) sum += __shfl_down(sum, off);
    __shared__ int sh[4];
    if ((threadIdx.x & 63) == 0) sh[threadIdx.x >> 6] = sum;
    __syncthreads();
    if (threadIdx.x == 0) partial[blk] = sh[0] + sh[1] + sh[2] + sh[3];
}

// K2b: per-chunk exclusive scan + chunk offset; write rs. (No cursor zeroing —
//      the fill kernels are atomic-free now.)
__global__ __launch_bounds__(256) void k_scan2(const int* __restrict__ cnt_n,
                                               int* __restrict__ rs_n,
                                               const int* __restrict__ cnt_s,
                                               int* __restrict__ rs_s,
                                               const int* __restrict__ partial) {
    int blk = blockIdx.x;
    int chunk = blk % NCH, wp = blk / NCH;
    int which = wp >> 4, pair = wp & 15;
    const int* cnt = (which ? cnt_s : cnt_n) + pair * MM;
    int* rs  = (which ? rs_s : rs_n) + pair * (MM + 1);
    __shared__ int sh[256];
    __shared__ int soff;
    if (threadIdx.x == 0) {
        int o = 0;
        for (int c = 0; c < chunk; ++c) o += partial[wp * NCH + c];
        soff = o;
        if (chunk == NCH - 1) rs[MM] = o + partial[wp * NCH + chunk];
    }
    int base = chunk * SCH + (int)threadIdx.x * 16;
    int v[16]; int run = 0;
    #pragma unroll
    for (int j = 0; j < 16; ++j) {
        int i = base + j;
        int c = (i < MM) ? cnt[i] : 0;
        v[j] = run;
        run += c;
    }
    sh[threadIdx.x] = run;
    __syncthreads();
    for (int off = 1; off < 256; off <<= 1) {
        int t = (threadIdx.x >= (unsigned)off) ? sh[threadIdx.x - off] : 0;
        __syncthreads();
        sh[threadIdx.x] += t;
        __syncthreads();
    }
    int texc = sh[threadIdx.x] - run;
    int o = soff + texc;
    #pragma unroll
    for (int j = 0; j < 16; ++j) {
        int i = base + j;
        if (i < MM) rs[i] = o + v[j];
    }
}

// ---------------------------------------------------------------------------
// K3: counting-sort neigh edges into merged-dst CSR — ATOMIC-FREE.
//     pos = rs_n[m] + grpoff[od] + rank8[i]. (src, weight) packed int2.
__global__ __launch_bounds__(256) void k_fill(const int* __restrict__ edge_src,
                                              const int* __restrict__ edge_dst,
                                              const int* __restrict__ merge,
                                              const int* __restrict__ deg_orig,
                                              const int* __restrict__ rs_n,
                                              const int* __restrict__ grpoff,
                                              const unsigned char* __restrict__ rank8,
                                              int2* __restrict__ csp) {
    int i = blockIdx.x * 256 + threadIdx.x;
    if (i >= P * P * EE) return;
    int pair = i / EE;
    int s = pair >> 2, d = pair & 3;
    int od = edge_dst[i];
    int m = (s == d) ? od : merge[pair * MM + od];
    float w = 1.0f / fmaxf((float)deg_orig[pair * MM + od], 1.0f);
    int pos = rs_n[pair * (MM + 1) + m] + grpoff[pair * MM + od] + (int)rank8[i];
    int2 e; e.x = edge_src[i]; e.y = __float_as_int(w);
    csp[(size_t)pair * EE + pos] = e;
}

// K3b: self-term CSR — ATOMIC-FREE. pos = rs_s[m] + selfrank[r].
__global__ __launch_bounds__(256) void k_fill_self(const int* __restrict__ merge,
                                                   const int* __restrict__ rs_s,
                                                   const int* __restrict__ selfrank,
                                                   int* __restrict__ css) {
    int i = blockIdx.x * 256 + threadIdx.x;
    if (i >= P * P * MM) return;
    int pair = i / MM;
    int r = i - pair * MM;
    int s = pair >> 2, d = pair & 3;
    int m = (s == d) ? r : merge[i];
    int pos = rs_s[pair * (MM + 1) + m] + selfrank[i];
    css[pair * MM + pos] = r;
}

// ---------------------------------------------------------------------------
// K3c: split weights into hi/lo bf16, packed fragment-ready:
//      Bpk[s][hl(2)][kchunk(32)][col(128)][8k]  (chunks 0-15 = W_self rows,
//      16-31 = W_neigh rows). 512 KB; overlaid on dead deg_orig space.
__global__ __launch_bounds__(256) void k_pack_w(const float* __restrict__ Ws,
                                                const float* __restrict__ Wn,
                                                unsigned short* __restrict__ Bpk) {
    int t = blockIdx.x * 256 + threadIdx.x;     // 4s * 32c * 128col = 16384
    if (t >= 4 * 32 * 128) return;
    int s = t >> 12;
    int rem = t & 4095;                         // c*128 + col
    int c = rem >> 7, col = rem & 127;
    const float* W = (c < 16) ? (Ws + (size_t)s * DD * DD + (c * 8) * DD + col)
                              : (Wn + (size_t)s * DD * DD + ((c - 16) * 8) * DD + col);
    size_t ohi = ((size_t)(s * 2 + 0) * 4096 + rem) * 8;
    size_t olo = ((size_t)(s * 2 + 1) * 4096 + rem) * 8;
    #pragma unroll
    for (int j = 0; j < 8; ++j) {
        float v = W[(size_t)j * DD];
        unsigned short h = bf16u(v);
        unsigned short l = bf16u(v - bf16f(h));
        Bpk[ohi + j] = h;
        Bpk[olo + j] = l;
    }
}

// ---------------------------------------------------------------------------
// K4: fused per-d kernel, 1024 threads / 16 waves. Round-5's proven gather
//     but each wave owns only 2 rows (halved latency chain); 2 blocks/CU =
//     32 waves/CU. GEMM: wave = one 16-row tile x one 16-col panel via
//     16x16x32 bf16 MFMA (hi*hi + lo*hi + hi*lo, fp32 accum).
__global__ __launch_bounds__(1024, 8) void k_fused(const float* __restrict__ x_all,
                                                   const float* __restrict__ b_all,
                                                   const int* __restrict__ rs_n_all,
                                                   const int2* __restrict__ csp_all,
                                                   const int* __restrict__ rs_s_all,
                                                   const int* __restrict__ css_all,
                                                   const unsigned short* __restrict__ Bpk,
                                                   float* __restrict__ out) {
    int d = blockIdx.y;
    int m0 = blockIdx.x * ROWS;
    int tid = threadIdx.x;
    int lane = tid & 63, wv = tid >> 6;         // wv in 0..15
    int l15 = lane & 15, kg = lane >> 4;

    // A_hi [32 rows][256 k] bf16 @0, A_lo @16384. Row stride 512 B.
    // XOR-swizzle byte ^= ((row&7)<<4) to break the 512B-stride bank conflict.
    __shared__ char lds[32768];

    f32x4 acc = {0.f, 0.f, 0.f, 0.f};

    int rt = wv & 1;                            // GEMM row tile 0/1
    int cp = wv >> 1;                           // GEMM col panel 0..7
    int colbase = cp * 16 + l15;

    for (int s = 0; s < P; ++s) {
        int pair = s * P + d;
        const float* x   = x_all + (size_t)s * NN * DD;
        const int* rsn   = rs_n_all + (size_t)pair * (MM + 1);
        const int2* csp  = csp_all + (size_t)pair * EE;
        const int* rss   = rs_s_all + (size_t)pair * (MM + 1);
        const int* css   = css_all + (size_t)pair * MM;

        // ---- gather: wave wv handles rows wv, wv+16. lane covers cols {2l, 2l+1}.
        for (int r = wv; r < ROWS; r += 16) {
            int m = m0 + r;
            float sx = 0.f, sy = 0.f, nx = 0.f, ny = 0.f;
            if (m < MM) {
                // self-scatter sum: identity on the diagonal, CSR else
                if (s == d) {
                    float2 v = ((const float2*)(x + (size_t)m * DD))[lane];
                    sx = v.x; sy = v.y;
                } else {
                    int e0 = rss[m], e1 = rss[m + 1];
                    for (int e = e0; e < e1; ++e) {
                        float2 v = ((const float2*)(x + (size_t)css[e] * DD))[lane];
                        sx += v.x; sy += v.y;
                    }
                }
                // weighted neigh sum (avg 8 rows), 4-wide unroll for MLP
                int e0 = rsn[m], e1 = rsn[m + 1];
                int e = e0;
                for (; e + 4 <= e1; e += 4) {
                    int2 c0 = csp[e], c1 = csp[e + 1], c2 = csp[e + 2], c3 = csp[e + 3];
                    float2 v0 = ((const float2*)(x + (size_t)c0.x * DD))[lane];
                    float2 v1 = ((const float2*)(x + (size_t)c1.x * DD))[lane];
                    float2 v2 = ((const float2*)(x + (size_t)c2.x * DD))[lane];
                    float2 v3 = ((const float2*)(x + (size_t)c3.x * DD))[lane];
                    float w0 = __int_as_float(c0.y), w1 = __int_as_float(c1.y);
                    float w2 = __int_as_float(c2.y), w3 = __int_as_float(c3.y);
                    nx += w0 * v0.x + w1 * v1.x + w2 * v2.x + w3 * v3.x;
                    ny += w0 * v0.y + w1 * v1.y + w2 * v2.y + w3 * v3.y;
                }
                for (; e < e1; ++e) {
                    int2 c = csp[e];
                    float w = __int_as_float(c.y);
                    float2 v = ((const float2*)(x + (size_t)c.x * DD))[lane];
                    nx += w * v.x; ny += w * v.y;
                }
            }
            // hi/lo bf16 split -> swizzled LDS. self half k[0,128), neigh k[128,256)
            int xr = (r & 7) << 4;
            int rbase = r * 512;
            unsigned short hx = bf16u(sx), hy = bf16u(sy);
            unsigned short lx = bf16u(sx - bf16f(hx)), ly = bf16u(sy - bf16f(hy));
            *(unsigned*)(lds + rbase + ((4 * lane) ^ xr))         = hx | ((unsigned)hy << 16);
            *(unsigned*)(lds + 16384 + rbase + ((4 * lane) ^ xr)) = lx | ((unsigned)ly << 16);
            hx = bf16u(nx); hy = bf16u(ny);
            lx = bf16u(nx - bf16f(hx)); ly = bf16u(ny - bf16f(hy));
            *(unsigned*)(lds + rbase + ((256 + 4 * lane) ^ xr))         = hx | ((unsigned)hy << 16);
            *(unsigned*)(lds + 16384 + rbase + ((256 + 4 * lane) ^ xr)) = lx | ((unsigned)ly << 16);
        }
        __syncthreads();

        // ---- MFMA GEMM: acc[16][16] += A[rt*16..+16][256] @ [Ws[s]; Wn[s]][:, cp*16..+16]
        {
            int row0 = rt * 16 + l15;
            int xr = (l15 & 7) << 4;
            const bf16x8* Bh = (const bf16x8*)(Bpk + (size_t)(s * 2 + 0) * 4096 * 8);
            const bf16x8* Bl = (const bf16x8*)(Bpk + (size_t)(s * 2 + 1) * 4096 * 8);
            #pragma unroll
            for (int kk = 0; kk < 8; ++kk) {
                int c = kk * 4 + kg;
                int co = (c * 16) ^ xr;
                bf16x8 ah = *(const bf16x8*)(lds + row0 * 512 + co);
                bf16x8 al = *(const bf16x8*)(lds + 16384 + row0 * 512 + co);
                size_t bo = (size_t)c * 128 + colbase;
                bf16x8 bh = Bh[bo];
                bf16x8 bl = Bl[bo];
                acc = __builtin_amdgcn_mfma_f32_16x16x32_bf16(ah, bh, acc, 0, 0, 0);
                acc = __builtin_amdgcn_mfma_f32_16x16x32_bf16(al, bh, acc, 0, 0, 0);
                acc = __builtin_amdgcn_mfma_f32_16x16x32_bf16(ah, bl, acc, 0, 0, 0);
            }
        }

        // ---- bias: each contributing source row brings one b[s]
        {
            float bv = b_all[(size_t)s * DD + colbase];
            int mb = m0 + rt * 16 + kg * 4;
            #pragma unroll
            for (int r = 0; r < 4; ++r) {
                int m = mb + r;
                if (m < MM) {
                    float cf = (float)(rss[m + 1] - rss[m]);
                    acc[r] += cf * bv;
                }
            }
        }
        __syncthreads();   // before next s overwrites LDS
    }

    // ---- store. D layout: col = lane&15 (+panel), row = (lane>>4)*4 + reg (+tile)
    float* outd = out + (size_t)d * MM * DD;
    #pragma unroll
    for (int r = 0; r < 4; ++r) {
        int m = m0 + rt * 16 + kg * 4 + r;
        if (m >= MM) continue;
        outd[(size_t)m * DD + colbase] = acc[r];
    }
}

// ---------------------------------------------------------------------------
extern "C" void kernel_launch(void* const* d_in, const int* in_sizes, int n_in,
                              void* d_out, int out_size, void* d_ws, size_t ws_size,
                              hipStream_t stream) {
    const float* x     = (const float*)d_in[0];   // [P][N][D]
    const float* Ws    = (const float*)d_in[1];   // [P][D][D]
    const float* Wn    = (const float*)d_in[2];   // [P][D][D]
    const float* b     = (const float*)d_in[3];   // [P][D]
    const int*   esrc  = (const int*)d_in[4];     // [P][P][E]
    const int*   edst  = (const int*)d_in[5];     // [P][P][E]
    const int*   merge = (const int*)d_in[6];     // [P][P][M]
    float* out = (float*)d_out;                   // [P][M][D]

    // workspace layout (~70.4 MB, unchanged):
    int* deg_orig = (int*)d_ws;                   // [16*M]; dead after k_fill -> Bpk
    int* cnt_n    = deg_orig + 16 * MM;           // [16*M] merged neigh counts
    int* cnt_s    = cnt_n + 16 * MM;              // [16*M] merged self counts
    int* rs_n     = cnt_s + 16 * MM;              // [16*(M+1)]
    int* rs_s     = rs_n + 16 * (MM + 1);         // [16*(M+1)]
    int2* csp     = (int2*)(rs_s + 16 * (MM + 1));// [16*E] packed (src, w)
    int* css      = (int*)(csp + (size_t)16 * EE);// [16*M]
    int* partial  = (int*)csp;                    // scan partials overlay (pre-fill)
    unsigned short* Bpk = (unsigned short*)d_ws;  // overlay on deg_orig

    // prep scratch in OUT (dead before k_fused, which fully overwrites out):
    int* grpoff   = (int*)out;                    // [16*M] 3.2 MB
    int* selfrank = grpoff + 16 * MM;             // [16*M] 3.2 MB
    unsigned char* rank8 = (unsigned char*)(selfrank + 16 * MM);  // [16*E] 6.4 MB

    hipMemsetAsync(d_ws, 0, sizeof(int) * (size_t)16 * MM * 3, stream);  // deg+cnt_n+cnt_s

    int eblocks = (P * P * EE + 255) / 256;       // 25000
    int mblocks16 = (P * P * MM + 255) / 256;     // 3125
    k_count<<<eblocks, 256, 0, stream>>>(edst, deg_orig, rank8);
    k_derive<<<mblocks16, 256, 0, stream>>>(merge, deg_orig, cnt_n, cnt_s, grpoff, selfrank);
    k_scan1<<<2 * 16 * NCH, 256, 0, stream>>>(cnt_n, cnt_s, partial);
    k_scan2<<<2 * 16 * NCH, 256, 0, stream>>>(cnt_n, rs_n, cnt_s, rs_s, partial);
    k_fill<<<eblocks, 256, 0, stream>>>(esrc, edst, merge, deg_orig, rs_n, grpoff, rank8, csp);
    k_fill_self<<<mblocks16, 256, 0, stream>>>(merge, rs_s, selfrank, css);
    k_pack_w<<<64, 256, 0, stream>>>(Ws, Wn, Bpk);  // overwrites deg_orig (dead)

    dim3 gfused((MM + ROWS - 1) / ROWS, P);       // (1563, 4)
    k_fused<<<gfused, 1024, 0, stream>>>(x, b, rs_n, csp, rs_s, css, Bpk, out);
}